// Round 7
// baseline (348.657 us; speedup 1.0000x reference)
//
#include <hip/hip_runtime.h>
#include <hip/hip_fp8.h>

#define S_LEN 512
#define BATCH 256
#define L 128
#define PAD_ID 0
#define START_ID 1

typedef int    i32x8 __attribute__((ext_vector_type(8)));
typedef int    i32x4 __attribute__((ext_vector_type(4)));
typedef float  f32x4 __attribute__((ext_vector_type(4)));
typedef unsigned int   u32x4 __attribute__((ext_vector_type(4)));
typedef unsigned short u16x2 __attribute__((ext_vector_type(2)));

__device__ __forceinline__ unsigned int umax2(unsigned int a, unsigned int b) {
    u16x2 x = __builtin_bit_cast(u16x2, a), y = __builtin_bit_cast(u16x2, b);
#if defined(__has_builtin) && __has_builtin(__builtin_elementwise_max)
    return __builtin_bit_cast(unsigned int, __builtin_elementwise_max(x, y));
#else
    u16x2 r; r.x = x.x > y.x ? x.x : y.x; r.y = x.y > y.y ? x.y : y.y;
    return __builtin_bit_cast(unsigned int, r);
#endif
}
__device__ __forceinline__ float frcp(float x) {
#if defined(__has_builtin) && __has_builtin(__builtin_amdgcn_rcpf)
    return __builtin_amdgcn_rcpf(x);
#else
    return 1.0f / x;
#endif
}
__device__ __forceinline__ unsigned short f2bf(float f) {   // RNE, f >= 0 here
    unsigned int u = __builtin_bit_cast(unsigned int, f);
    return (unsigned short)((u + 0x7fffu + ((u >> 16) & 1u)) >> 16);
}
__device__ __forceinline__ float bf2f(unsigned short b) {
    return __builtin_bit_cast(float, (unsigned int)b << 16);
}
// pack 4 positive floats -> 4 fp8 e4m3 bytes in one dword
__device__ __forceinline__ int pk4_fp8(float a, float b, float c, float d) {
#if defined(__has_builtin) && __has_builtin(__builtin_amdgcn_cvt_pk_fp8_f32)
    int w = __builtin_amdgcn_cvt_pk_fp8_f32(a, b, 0, false);
    w = __builtin_amdgcn_cvt_pk_fp8_f32(c, d, w, true);
    return w;
#else
    __hip_fp8_e4m3 A(a), B(b), C(c), D(d);
    return (int)A.__x | ((int)B.__x << 8) | ((int)C.__x << 16) | ((int)D.__x << 24);
#endif
}

// One 64-lane wave per batch row, NO barriers (same-wave DS ordering).
// cur = q(1x128) @ expT(128x128) via 8x mfma_scale_f32_16x16x128_f8f6f4 (scale=1.0
// = E8M0 127): one MFMA per 16-label tile covers all of K=128 -> issue 155 cyc vs 620
// (r5 bf16) and no __syncthreads vs r6. q = 128 fp8 bytes in LDS, PERMUTED store order
// store[8m+nt] = label 16nt+m: A = 2 broadcast ds_read_b128; lane's 8 outputs contiguous
// -> 1 ds_write_b64. B (expT) is built with the same slot->k mapping, so any HW k-layout
// permutation cancels in the dot (r5-verified trick). Scale: depth-0 feedback only
// (r4 lesson: lagged scales oscillate/overflow) via per-lane-max hint array; fp8 sat
// insurance fminf(p,400). 5 LDS instr/step total.
__global__ __launch_bounds__(64, 1) void k_scan(
        const float* __restrict__ emit, const int* __restrict__ labels,
        const void* __restrict__ masks, const float* __restrict__ T,
        float* __restrict__ out) {
    const int b = blockIdx.x;
    const int lane = threadIdx.x;            // 0..63
    const int g = lane >> 4, m = lane & 15;  // quad (k-chunk), col

    __shared__ __align__(16) unsigned char qs[512];  // [0,128) live; rest g>0 scratch
    __shared__ __align__(16) short hint[64];         // per-lane max, bf16 bits

    // ---- mask encoding self-detect (first 8KB; uniform across blocks) ----
    const unsigned int* mw0 = (const unsigned int*)masks;
    int pred = 0;
    #pragma unroll
    for (int k = 0; k < 32; ++k) {
        unsigned int w0 = mw0[lane + 64 * k];
        pred |= (w0 > 1u && w0 != 0x3f800000u);
    }
    const bool isbyte = (__ballot(pred) != 0ull);

    // ---- length of row b (prefix-ones mask) ----
    int len;
    {
        int cnt = 0;
        if (isbyte) {
            const unsigned int* mw = (const unsigned int*)masks + b * (S_LEN / 4);
            #pragma unroll
            for (int k = 0; k < 2; ++k) {
                unsigned int w0 = mw[lane + 64 * k];
                cnt += ((w0 & 0xffu) != 0) + ((w0 & 0xff00u) != 0) +
                       ((w0 & 0xff0000u) != 0) + ((w0 & 0xff000000u) != 0);
            }
        } else {
            const unsigned int* mw = (const unsigned int*)masks + b * S_LEN;
            #pragma unroll
            for (int k = 0; k < 8; ++k) cnt += (mw[lane + 64 * k] != 0u);
        }
        #pragma unroll
        for (int off = 32; off; off >>= 1) cnt += __shfl_xor(cnt, off, 64);
        len = cnt;
    }

    // ---- B-frags: byte slot s = 32g + 4d + y holds expT[j(s)][16nt+m],
    //      j(s) = 16*(s&7) + (s>>3)  (the store-order permutation) ----
#define LDB(BF, nt)                                                                          \
    {                                                                                        \
        _Pragma("unroll")                                                                    \
        for (int d = 0; d < 8; ++d) {                                                        \
            int s0 = 32 * g + 4 * d;                                                         \
            float v0 = __expf(T[(16 * ((s0 + 0) & 7) + ((s0 + 0) >> 3)) * L + 16 * (nt) + m]); \
            float v1 = __expf(T[(16 * ((s0 + 1) & 7) + ((s0 + 1) >> 3)) * L + 16 * (nt) + m]); \
            float v2 = __expf(T[(16 * ((s0 + 2) & 7) + ((s0 + 2) >> 3)) * L + 16 * (nt) + m]); \
            float v3 = __expf(T[(16 * ((s0 + 3) & 7) + ((s0 + 3) >> 3)) * L + 16 * (nt) + m]); \
            BF[d] = pk4_fp8(v0, v1, v2, v3);                                                 \
        }                                                                                    \
    }
    i32x8 Bf0, Bf1, Bf2, Bf3, Bf4, Bf5, Bf6, Bf7;
    LDB(Bf0, 0) LDB(Bf1, 1) LDB(Bf2, 2) LDB(Bf3, 3)
    LDB(Bf4, 4) LDB(Bf5, 5) LDB(Bf6, 6) LDB(Bf7, 7)

    // ---- fs0 (labels 16nt+m), exact wave max -> S, q0 ----
    float p0, p1, p2, p3, p4, p5, p6, p7, S;
    {
        float f[8];
        #pragma unroll
        for (int nt = 0; nt < 8; ++nt)
            f[nt] = emit[b * L + 16 * nt + m] + T[START_ID * L + 16 * nt + m];
        float mx = f[0];
        #pragma unroll
        for (int nt = 1; nt < 8; ++nt) mx = fmaxf(mx, f[nt]);
        #pragma unroll
        for (int off = 32; off; off >>= 1) mx = fmaxf(mx, __shfl_xor(mx, off, 64));
        S = mx;
        p0 = __expf(f[0] - S); p1 = __expf(f[1] - S);
        p2 = __expf(f[2] - S); p3 = __expf(f[3] - S);
        p4 = __expf(f[4] - S); p5 = __expf(f[5] - S);
        p6 = __expf(f[6] - S); p7 = __expf(f[7] - S);
        *(int2*)(qs + 8 * lane) = make_int2(pk4_fp8(p0, p1, p2, p3),
                                            pk4_fp8(p4, p5, p6, p7));
        float lm = fmaxf(fmaxf(fmaxf(p0, p1), fmaxf(p2, p3)),
                         fmaxf(fmaxf(p4, p5), fmaxf(p6, p7)));
        hint[lane] = (short)f2bf(lm);
    }

    // ---- emit prefetch, 2 steps deep ----
    float xe[8], er[8];
    #pragma unroll
    for (int nt = 0; nt < 8; ++nt) {
        xe[nt] = (len > 1) ? __expf(emit[(1 * BATCH + b) * L + 16 * nt + m]) : 1.0f;
        er[nt] = (len > 2) ? emit[(2 * BATCH + b) * L + 16 * nt + m] : 0.0f;
    }

    const f32x4 z = {0.f, 0.f, 0.f, 0.f};
    for (int t = 1; t < len; ++t) {
        i32x4 alo = *(const i32x4*)(qs + 32 * g);
        i32x4 ahi = *(const i32x4*)(qs + 32 * g + 16);
        i32x8 A;
        A[0] = alo[0]; A[1] = alo[1]; A[2] = alo[2]; A[3] = alo[3];
        A[4] = ahi[0]; A[5] = ahi[1]; A[6] = ahi[2]; A[7] = ahi[3];

        u32x4 h = *(const u32x4*)hint;            // uniform: hint[0..7]
        unsigned int um = umax2(umax2(h.x, h.y), umax2(h.z, h.w));
        u16x2 uh = __builtin_bit_cast(u16x2, um);
        float msc = fmaxf(bf2f(uh.x > uh.y ? uh.x : uh.y), 1e-20f);
        float kk = frcp(msc);

        float ld[8];
        #pragma unroll
        for (int nt = 0; nt < 8; ++nt)
            ld[nt] = (t + 2 < len) ? emit[((t + 2) * BATCH + b) * L + 16 * nt + m] : 0.0f;

        f32x4 c0 = __builtin_amdgcn_mfma_scale_f32_16x16x128_f8f6f4(A, Bf0, z, 0, 0, 0, 127, 0, 127);
        f32x4 c1 = __builtin_amdgcn_mfma_scale_f32_16x16x128_f8f6f4(A, Bf1, z, 0, 0, 0, 127, 0, 127);
        f32x4 c2 = __builtin_amdgcn_mfma_scale_f32_16x16x128_f8f6f4(A, Bf2, z, 0, 0, 0, 127, 0, 127);
        f32x4 c3 = __builtin_amdgcn_mfma_scale_f32_16x16x128_f8f6f4(A, Bf3, z, 0, 0, 0, 127, 0, 127);
        f32x4 c4 = __builtin_amdgcn_mfma_scale_f32_16x16x128_f8f6f4(A, Bf4, z, 0, 0, 0, 127, 0, 127);
        f32x4 c5 = __builtin_amdgcn_mfma_scale_f32_16x16x128_f8f6f4(A, Bf5, z, 0, 0, 0, 127, 0, 127);
        f32x4 c6 = __builtin_amdgcn_mfma_scale_f32_16x16x128_f8f6f4(A, Bf6, z, 0, 0, 0, 127, 0, 127);
        f32x4 c7 = __builtin_amdgcn_mfma_scale_f32_16x16x128_f8f6f4(A, Bf7, z, 0, 0, 0, 127, 0, 127);

        p0 = fminf(c0[0] * kk * xe[0], 400.f);    // rows replicated: c[0] valid everywhere
        p1 = fminf(c1[0] * kk * xe[1], 400.f);
        p2 = fminf(c2[0] * kk * xe[2], 400.f);
        p3 = fminf(c3[0] * kk * xe[3], 400.f);
        p4 = fminf(c4[0] * kk * xe[4], 400.f);
        p5 = fminf(c5[0] * kk * xe[5], 400.f);
        p6 = fminf(c6[0] * kk * xe[6], 400.f);
        p7 = fminf(c7[0] * kk * xe[7], 400.f);
        S += __logf(msc);

        *(int2*)(qs + 8 * lane) = make_int2(pk4_fp8(p0, p1, p2, p3),
                                            pk4_fp8(p4, p5, p6, p7));
        float lm = fmaxf(fmaxf(fmaxf(p0, p1), fmaxf(p2, p3)),
                         fmaxf(fmaxf(p4, p5), fmaxf(p6, p7)));
        hint[lane] = (short)f2bf(lm);

        #pragma unroll
        for (int nt = 0; nt < 8; ++nt) { xe[nt] = __expf(er[nt]); er[nt] = ld[nt]; }
    }

    // ---- encode_b = S + log(sum_j q_j * expT[j][PAD]) (labels duplicated x4 over g) ----
    float ev = 0.f;
    if (g == 0) {
        float e0 = __expf(T[(16 * 0 + m) * L + PAD_ID]), e1 = __expf(T[(16 * 1 + m) * L + PAD_ID]);
        float e2 = __expf(T[(16 * 2 + m) * L + PAD_ID]), e3 = __expf(T[(16 * 3 + m) * L + PAD_ID]);
        float e4 = __expf(T[(16 * 4 + m) * L + PAD_ID]), e5 = __expf(T[(16 * 5 + m) * L + PAD_ID]);
        float e6 = __expf(T[(16 * 6 + m) * L + PAD_ID]), e7 = __expf(T[(16 * 7 + m) * L + PAD_ID]);
        ev = ((p0 * e0 + p1 * e1) + (p2 * e2 + p3 * e3))
           + ((p4 * e4 + p5 * e5) + (p6 * e6 + p7 * e7));
    }
    #pragma unroll
    for (int off = 32; off; off >>= 1) ev += __shfl_xor(ev, off, 64);
    float enc = S + __logf(ev);

    // ---- gold_b ----
    float gsum = 0.f;
    for (int t = lane; t < len; t += 64) {
        int nxt = labels[b * S_LEN + t];
        int prv = t ? labels[b * S_LEN + t - 1] : START_ID;
        gsum += emit[(t * BATCH + b) * L + nxt] + T[prv * L + nxt];
        if (t == len - 1) gsum += T[nxt * L + PAD_ID];
    }
    #pragma unroll
    for (int off = 32; off; off >>= 1) gsum += __shfl_xor(gsum, off, 64);

    if (lane == 0) atomicAdd(out, enc - gsum);
}

extern "C" void kernel_launch(void* const* d_in, const int* in_sizes, int n_in,
                              void* d_out, int out_size, void* d_ws, size_t ws_size,
                              hipStream_t stream) {
    const float* emit   = (const float*)d_in[0];
    const int*   labels = (const int*)d_in[1];
    const void*  masks  = d_in[2];
    const float* T      = (const float*)d_in[3];
    float* out = (float*)d_out;

    hipMemsetAsync(d_out, 0, sizeof(float), stream);
    k_scan<<<dim3(BATCH), dim3(64), 0, stream>>>(emit, labels, masks, T, out);
}

// Round 8
// 326.319 us; speedup vs baseline: 1.0685x; 1.0685x over previous
//
#include <hip/hip_runtime.h>
#include <hip/hip_fp8.h>

#define S_LEN 512
#define BATCH 256
#define L 128
#define PAD_ID 0
#define START_ID 1

typedef int    i32x8 __attribute__((ext_vector_type(8)));
typedef int    i32x4 __attribute__((ext_vector_type(4)));
typedef float  f32x4 __attribute__((ext_vector_type(4)));
typedef unsigned int   u32x4 __attribute__((ext_vector_type(4)));
typedef unsigned short u16x2 __attribute__((ext_vector_type(2)));

__device__ __forceinline__ unsigned int umax2(unsigned int a, unsigned int b) {
    u16x2 x = __builtin_bit_cast(u16x2, a), y = __builtin_bit_cast(u16x2, b);
#if defined(__has_builtin) && __has_builtin(__builtin_elementwise_max)
    return __builtin_bit_cast(unsigned int, __builtin_elementwise_max(x, y));  // v_pk_max_u16
#else
    u16x2 r; r.x = x.x > y.x ? x.x : y.x; r.y = x.y > y.y ? x.y : y.y;
    return __builtin_bit_cast(unsigned int, r);
#endif
}
__device__ __forceinline__ float frcp(float x) {
#if defined(__has_builtin) && __has_builtin(__builtin_amdgcn_rcpf)
    return __builtin_amdgcn_rcpf(x);
#else
    return 1.0f / x;
#endif
}
// pack 2 positive floats -> 2 fp8 e4m3 bytes (low 16 bits)
__device__ __forceinline__ int pk2_fp8(float a, float b) {
#if defined(__has_builtin) && __has_builtin(__builtin_amdgcn_cvt_pk_fp8_f32)
    return __builtin_amdgcn_cvt_pk_fp8_f32(a, b, 0, false);
#else
    __hip_fp8_e4m3 A(a), B(b);
    return (int)A.__x | ((int)B.__x << 8);
#endif
}
// exact max byte (u8) over 8 dwords of positive-e4m3 bytes, via even/odd u16 lanes
__device__ __forceinline__ unsigned int bmax8(u32x4 a, u32x4 b) {
    const unsigned int M = 0x00FF00FFu;
    unsigned int l0 = umax2(a.x & M, a.y & M), l1 = umax2(a.z & M, a.w & M);
    unsigned int l2 = umax2(b.x & M, b.y & M), l3 = umax2(b.z & M, b.w & M);
    unsigned int h0 = umax2((a.x >> 8) & M, (a.y >> 8) & M);
    unsigned int h1 = umax2((a.z >> 8) & M, (a.w >> 8) & M);
    unsigned int h2 = umax2((b.x >> 8) & M, (b.y >> 8) & M);
    unsigned int h3 = umax2((b.z >> 8) & M, (b.w >> 8) & M);
    unsigned int v = umax2(umax2(umax2(l0, l1), umax2(l2, l3)),
                           umax2(umax2(h0, h1), umax2(h2, h3)));
    u16x2 t = __builtin_bit_cast(u16x2, v);
    return (unsigned int)(t.x > t.y ? t.x : t.y);
}
// decode e4m3 byte -> float
__device__ __forceinline__ float fp8dec(unsigned int bb) {
    int e = (int)(bb >> 3), mt = (int)(bb & 7u);
    float v = e ? __builtin_ldexpf((float)(8 + mt), e - 10)
                : __builtin_ldexpf((float)mt, -9);
    return fmaxf(v, 1e-9f);
}

// One block (4 waves) per batch row; wave w owns output labels [32w, 32w+32).
// cur = q(1x128) @ expT(128x128): per wave 2x mfma_scale_f32_16x16x128_f8f6f4
// (8 MFMAs spread over 4 SIMDs = minimal ~138-cyc pipe span; r7 lesson: 8 on one
// SIMD = 553). q = 128 fp8 bytes, double-buffered; A = 2 broadcast ds_read_b128,
// q-write = 1 ds_write_b16 (permuted store slot 8m+nt = label 16nt+m, same map
// baked into B so it cancels — r5/r7-verified). Scale: EXACT lag-free max — each
// quad SWAR-u8-maxes its 32 A-bytes (e4m3>=0 orders as u8), one lane/quad writes
// hint byte; next step ds_read_b32 + 5 ops = exact max of all 128 bytes, uniform.
// Emit prefetched in 8-step register chunks (r6) -> vmcnt drains amortized.
__global__ __launch_bounds__(256, 1) void k_scan(
        const float* __restrict__ emit, const int* __restrict__ labels,
        const void* __restrict__ masks, const float* __restrict__ T,
        float* __restrict__ out) {
    const int b = blockIdx.x;
    const int tid = threadIdx.x;
    const int w = tid >> 6;                  // wave 0..3
    const int lane = tid & 63;
    const int g = lane >> 4, m = lane & 15;  // quad (k-chunk), col
    const int ja = 32 * w + m, jb = ja + 16; // this wave's two output labels

    __shared__ __align__(16) unsigned char qs[2][128];
    __shared__ __align__(8)  unsigned char hb[8];    // hint bytes, [buf*4 + quad]
    __shared__ float part[8];
    __shared__ float fsx[4];
    __shared__ int   ib[4];

    // ---- mask encoding self-detect (first 8KB; block-uniform) ----
    {
        const unsigned int* mw0 = (const unsigned int*)masks;
        int pred = 0;
        #pragma unroll
        for (int k = 0; k < 8; ++k) {
            unsigned int w0 = mw0[tid + 256 * k];
            pred |= (w0 > 1u && w0 != 0x3f800000u);
        }
        unsigned long long bal = __ballot(pred);
        if (lane == 0) ib[w] = (bal != 0ull) ? 1 : 0;
        if (tid < 8) hb[tid] = 0x38;         // fp8(1.0): q0 max is exactly 1
    }
    __syncthreads();
    const bool isbyte = (ib[0] | ib[1] | ib[2] | ib[3]) != 0;

    // ---- len of row b (prefix-ones mask; per-wave redundant, uniform) ----
    int len;
    {
        int cnt = 0;
        if (isbyte) {
            const unsigned int* mw = (const unsigned int*)masks + b * (S_LEN / 4);
            #pragma unroll
            for (int k = 0; k < 2; ++k) {
                unsigned int w0 = mw[lane + 64 * k];
                cnt += ((w0 & 0xffu) != 0) + ((w0 & 0xff00u) != 0) +
                       ((w0 & 0xff0000u) != 0) + ((w0 & 0xff000000u) != 0);
            }
        } else {
            const unsigned int* mw = (const unsigned int*)masks + b * S_LEN;
            #pragma unroll
            for (int k = 0; k < 8; ++k) cnt += (mw[lane + 64 * k] != 0u);
        }
        #pragma unroll
        for (int off = 32; off; off >>= 1) cnt += __shfl_xor(cnt, off, 64);
        len = cnt;
    }

    // ---- B-frags (2 N-tiles per wave): byte slot s = 32g+4d+y holds
    //      expT[j(s)][16nt+m], j(s) = 16*(s&7) + (s>>3) ----
#define LDB(BF, nt)                                                                          \
    {                                                                                        \
        _Pragma("unroll")                                                                    \
        for (int d = 0; d < 8; ++d) {                                                        \
            int s0 = 32 * g + 4 * d;                                                         \
            float v0 = __expf(T[(16 * ((s0 + 0) & 7) + ((s0 + 0) >> 3)) * L + 16 * (nt) + m]); \
            float v1 = __expf(T[(16 * ((s0 + 1) & 7) + ((s0 + 1) >> 3)) * L + 16 * (nt) + m]); \
            float v2 = __expf(T[(16 * ((s0 + 2) & 7) + ((s0 + 2) >> 3)) * L + 16 * (nt) + m]); \
            float v3 = __expf(T[(16 * ((s0 + 3) & 7) + ((s0 + 3) >> 3)) * L + 16 * (nt) + m]); \
            int p01 = pk2_fp8(v0, v1), p23 = pk2_fp8(v2, v3);                                \
            BF[d] = (p01 & 0xffff) | (p23 << 16);                                            \
        }                                                                                    \
    }
    i32x8 Bf0, Bf1;
    LDB(Bf0, 2 * w) LDB(Bf1, 2 * w + 1)

    float eTpa = __expf(T[ja * L + PAD_ID]);
    float eTpb = __expf(T[jb * L + PAD_ID]);

    // ---- fs0, exact block max -> S, q0 ----
    float fa  = emit[b * L + ja] + T[START_ID * L + ja];
    float fbv = emit[b * L + jb] + T[START_ID * L + jb];
    float mx = fmaxf(fa, fbv);
    #pragma unroll
    for (int off = 32; off; off >>= 1) mx = fmaxf(mx, __shfl_xor(mx, off, 64));
    if (lane == 0) fsx[w] = mx;
    __syncthreads();
    float S = fmaxf(fmaxf(fsx[0], fsx[1]), fmaxf(fsx[2], fsx[3]));
    float p0 = __expf(fa - S), p1 = __expf(fbv - S);
    if (g == 0)
        *(short*)&qs[0][8 * m + 2 * w] = (short)(pk2_fp8(p0, p1) & 0xffff);
    __syncthreads();

    // ---- emit prefetch: 8-step register chunks, one chunk ahead ----
    float eca[8], ecb[8], ena[8], enb[8];
    #pragma unroll
    for (int k = 0; k < 8; ++k) {
        int tt = 1 + k;
        eca[k] = (tt < len) ? emit[(tt * BATCH + b) * L + ja] : 0.f;
        ecb[k] = (tt < len) ? emit[(tt * BATCH + b) * L + jb] : 0.f;
    }

    const f32x4 z = {0.f, 0.f, 0.f, 0.f};
    for (int base = 1; base < len; base += 8) {
        #pragma unroll
        for (int k = 0; k < 8; ++k) {
            int tt = base + 8 + k;
            ena[k] = (tt < len) ? emit[(tt * BATCH + b) * L + ja] : 0.f;
            enb[k] = (tt < len) ? emit[(tt * BATCH + b) * L + jb] : 0.f;
        }
        #pragma unroll
        for (int k = 0; k < 8; ++k) {
            int t = base + k;
            if (t >= len) break;                 // uniform across block
            const int rb = (t - 1) & 1, wb = t & 1;

            float xe0 = __expf(eca[k]), xe1 = __expf(ecb[k]);   // off dep-path

            i32x4 alo = *(const i32x4*)&qs[rb][32 * g];
            i32x4 ahi = *(const i32x4*)&qs[rb][32 * g + 16];
            unsigned int hd = *(const unsigned int*)&hb[rb * 4];

            // exact uniform max of q_{t-1}: 4 hint bytes -> u8 max -> decode
            {
                const unsigned int M = 0x00FF00FFu;
                unsigned int v = umax2(hd & M, (hd >> 8) & M);
                u16x2 tv = __builtin_bit_cast(u16x2, v);
                hd = (unsigned int)(tv.x > tv.y ? tv.x : tv.y);
            }
            float msc = fp8dec(hd);
            float kk = frcp(msc);

            i32x8 A;
            A[0] = alo[0]; A[1] = alo[1]; A[2] = alo[2]; A[3] = alo[3];
            A[4] = ahi[0]; A[5] = ahi[1]; A[6] = ahi[2]; A[7] = ahi[3];

            f32x4 c0 = __builtin_amdgcn_mfma_scale_f32_16x16x128_f8f6f4(A, Bf0, z, 0, 0, 0, 127, 0, 127);
            f32x4 c1 = __builtin_amdgcn_mfma_scale_f32_16x16x128_f8f6f4(A, Bf1, z, 0, 0, 0, 127, 0, 127);

            // per-quad exact byte-max of A -> hint for next step (off critical path)
            unsigned int qm = bmax8(__builtin_bit_cast(u32x4, alo),
                                    __builtin_bit_cast(u32x4, ahi));
            if (w == 0 && m == 0) hb[wb * 4 + g] = (unsigned char)qm;

            p0 = fminf(c0[0] * kk * xe0, 400.f);   // rows replicated: c[0] valid
            p1 = fminf(c1[0] * kk * xe1, 400.f);
            if (g == 0)
                *(short*)&qs[wb][8 * m + 2 * w] = (short)(pk2_fp8(p0, p1) & 0xffff);
            S += __logf(msc);
            __syncthreads();
        }
        #pragma unroll
        for (int k = 0; k < 8; ++k) { eca[k] = ena[k]; ecb[k] = enb[k]; }
    }

    // ---- encode_b = S + log(sum_j q_j * expT[j][PAD]) (dedup over g) ----
    float ev = (g == 0) ? (p0 * eTpa + p1 * eTpb) : 0.f;
    #pragma unroll
    for (int off = 32; off; off >>= 1) ev += __shfl_xor(ev, off, 64);
    if (lane == 0) part[w] = ev;

    // ---- gold_b over all 256 threads ----
    float gsum = 0.f;
    for (int t = tid; t < len; t += 256) {
        int nxt = labels[b * S_LEN + t];
        int prv = t ? labels[b * S_LEN + t - 1] : START_ID;
        gsum += emit[(t * BATCH + b) * L + nxt] + T[prv * L + nxt];
        if (t == len - 1) gsum += T[nxt * L + PAD_ID];
    }
    #pragma unroll
    for (int off = 32; off; off >>= 1) gsum += __shfl_xor(gsum, off, 64);
    if (lane == 0) part[4 + w] = gsum;
    __syncthreads();

    if (tid == 0) {
        float enc  = S + __logf((part[0] + part[1]) + (part[2] + part[3]));
        float gold = (part[4] + part[5]) + (part[6] + part[7]);
        atomicAdd(out, enc - gold);
    }
}

extern "C" void kernel_launch(void* const* d_in, const int* in_sizes, int n_in,
                              void* d_out, int out_size, void* d_ws, size_t ws_size,
                              hipStream_t stream) {
    const float* emit   = (const float*)d_in[0];
    const int*   labels = (const int*)d_in[1];
    const void*  masks  = d_in[2];
    const float* T      = (const float*)d_in[3];
    float* out = (float*)d_out;

    hipMemsetAsync(d_out, 0, sizeof(float), stream);
    k_scan<<<dim3(BATCH), dim3(256), 0, stream>>>(emit, labels, masks, T, out);
}

// Round 9
// 299.589 us; speedup vs baseline: 1.1638x; 1.0892x over previous
//
#include <hip/hip_runtime.h>
#include <hip/hip_fp8.h>

#define S_LEN 512
#define BATCH 256
#define L 128
#define PAD_ID 0
#define START_ID 1
#define PHASE_T 254   // emit rows staged in LDS per phase (254*128*2B = 65024 B)

typedef int    i32x8 __attribute__((ext_vector_type(8)));
typedef int    i32x4 __attribute__((ext_vector_type(4)));
typedef float  f32x4 __attribute__((ext_vector_type(4)));
typedef unsigned int   u32x4 __attribute__((ext_vector_type(4)));
typedef unsigned short u16x2 __attribute__((ext_vector_type(2)));

__device__ __forceinline__ unsigned int umax2(unsigned int a, unsigned int b) {
    u16x2 x = __builtin_bit_cast(u16x2, a), y = __builtin_bit_cast(u16x2, b);
#if defined(__has_builtin) && __has_builtin(__builtin_elementwise_max)
    return __builtin_bit_cast(unsigned int, __builtin_elementwise_max(x, y));  // v_pk_max_u16
#else
    u16x2 r; r.x = x.x > y.x ? x.x : y.x; r.y = x.y > y.y ? x.y : y.y;
    return __builtin_bit_cast(unsigned int, r);
#endif
}
__device__ __forceinline__ float frcp(float x) {
#if defined(__has_builtin) && __has_builtin(__builtin_amdgcn_rcpf)
    return __builtin_amdgcn_rcpf(x);
#else
    return 1.0f / x;
#endif
}
__device__ __forceinline__ unsigned short f2bf(float f) {   // RNE f32->bf16 (any sign)
    unsigned int u = __builtin_bit_cast(unsigned int, f);
    return (unsigned short)((u + 0x7fffu + ((u >> 16) & 1u)) >> 16);
}
__device__ __forceinline__ float bf2f(unsigned short b) {
    return __builtin_bit_cast(float, (unsigned int)b << 16);
}
// pack 2 positive floats -> 2 fp8 e4m3 bytes (low 16 bits)
__device__ __forceinline__ int pk2_fp8(float a, float b) {
#if defined(__has_builtin) && __has_builtin(__builtin_amdgcn_cvt_pk_fp8_f32)
    return __builtin_amdgcn_cvt_pk_fp8_f32(a, b, 0, false);
#else
    __hip_fp8_e4m3 A(a), B(b);
    return (int)A.__x | ((int)B.__x << 8);
#endif
}
// exact max byte (u8) over 8 dwords of positive-e4m3 bytes, via even/odd u16 lanes
__device__ __forceinline__ unsigned int bmax8(u32x4 a, u32x4 b) {
    const unsigned int M = 0x00FF00FFu;
    unsigned int l0 = umax2(a.x & M, a.y & M), l1 = umax2(a.z & M, a.w & M);
    unsigned int l2 = umax2(b.x & M, b.y & M), l3 = umax2(b.z & M, b.w & M);
    unsigned int h0 = umax2((a.x >> 8) & M, (a.y >> 8) & M);
    unsigned int h1 = umax2((a.z >> 8) & M, (a.w >> 8) & M);
    unsigned int h2 = umax2((b.x >> 8) & M, (b.y >> 8) & M);
    unsigned int h3 = umax2((b.z >> 8) & M, (b.w >> 8) & M);
    unsigned int v = umax2(umax2(umax2(l0, l1), umax2(l2, l3)),
                           umax2(umax2(h0, h1), umax2(h2, h3)));
    u16x2 t = __builtin_bit_cast(u16x2, v);
    return (unsigned int)(t.x > t.y ? t.x : t.y);
}
// decode e4m3 byte -> float
__device__ __forceinline__ float fp8dec(unsigned int bb) {
    int e = (int)(bb >> 3), mt = (int)(bb & 7u);
    float v = e ? __builtin_ldexpf((float)(8 + mt), e - 10)
                : __builtin_ldexpf((float)mt, -9);
    return fmaxf(v, 1e-9f);
}

// r8 structure (4 waves/row, fp8 q, 2x mfma_scale_16x16x128/wave, exact u8 hint max,
// one barrier/step) + THE r9 CHANGE: the scan loop contains ZERO global-memory
// instructions. Emit is staged into LDS as bf16 in 254-step phases (64 KB buffer,
// coalesced float2 loads -> ds_write_b32 by all 256 threads). The per-step
// __syncthreads therefore drains only lgkmcnt (tiny LDS writes) — no vmcnt(0)
// L3-latency drain in the hot loop (m97 lesson). Emit bf16 error ~1.4 abs total
// vs threshold 7700; gold path still reads exact f32 emit from global.
__global__ __launch_bounds__(256, 1) void k_scan(
        const float* __restrict__ emit, const int* __restrict__ labels,
        const void* __restrict__ masks, const float* __restrict__ T,
        float* __restrict__ out) {
    const int b = blockIdx.x;
    const int tid = threadIdx.x;
    const int w = tid >> 6;                  // wave 0..3
    const int lane = tid & 63;
    const int g = lane >> 4, m = lane & 15;  // quad (k-chunk), col
    const int ja = 32 * w + m, jb = ja + 16; // this wave's two output labels

    __shared__ unsigned short elds[PHASE_T * L];     // emit rows, bf16, [row][j]
    __shared__ __align__(16) unsigned char qs[2][128];
    __shared__ __align__(8)  unsigned char hb[8];    // hint bytes, [buf*4 + quad]
    __shared__ float part[8];
    __shared__ float fsx[4];
    __shared__ int   ib[4];

    // ---- mask encoding self-detect (first 8KB; block-uniform) ----
    {
        const unsigned int* mw0 = (const unsigned int*)masks;
        int pred = 0;
        #pragma unroll
        for (int k = 0; k < 8; ++k) {
            unsigned int w0 = mw0[tid + 256 * k];
            pred |= (w0 > 1u && w0 != 0x3f800000u);
        }
        unsigned long long bal = __ballot(pred);
        if (lane == 0) ib[w] = (bal != 0ull) ? 1 : 0;
        if (tid < 8) hb[tid] = 0x38;         // fp8(1.0): q0 max is exactly 1
    }
    __syncthreads();
    const bool isbyte = (ib[0] | ib[1] | ib[2] | ib[3]) != 0;

    // ---- len of row b (prefix-ones mask; per-wave redundant, uniform) ----
    int len;
    {
        int cnt = 0;
        if (isbyte) {
            const unsigned int* mw = (const unsigned int*)masks + b * (S_LEN / 4);
            #pragma unroll
            for (int k = 0; k < 2; ++k) {
                unsigned int w0 = mw[lane + 64 * k];
                cnt += ((w0 & 0xffu) != 0) + ((w0 & 0xff00u) != 0) +
                       ((w0 & 0xff0000u) != 0) + ((w0 & 0xff000000u) != 0);
            }
        } else {
            const unsigned int* mw = (const unsigned int*)masks + b * S_LEN;
            #pragma unroll
            for (int k = 0; k < 8; ++k) cnt += (mw[lane + 64 * k] != 0u);
        }
        #pragma unroll
        for (int off = 32; off; off >>= 1) cnt += __shfl_xor(cnt, off, 64);
        len = cnt;
    }

    // ---- B-frags (2 N-tiles per wave): byte slot s = 32g+4d+y holds
    //      expT[j(s)][16nt+m], j(s) = 16*(s&7) + (s>>3) ----
#define LDB(BF, nt)                                                                          \
    {                                                                                        \
        _Pragma("unroll")                                                                    \
        for (int d = 0; d < 8; ++d) {                                                        \
            int s0 = 32 * g + 4 * d;                                                         \
            float v0 = __expf(T[(16 * ((s0 + 0) & 7) + ((s0 + 0) >> 3)) * L + 16 * (nt) + m]); \
            float v1 = __expf(T[(16 * ((s0 + 1) & 7) + ((s0 + 1) >> 3)) * L + 16 * (nt) + m]); \
            float v2 = __expf(T[(16 * ((s0 + 2) & 7) + ((s0 + 2) >> 3)) * L + 16 * (nt) + m]); \
            float v3 = __expf(T[(16 * ((s0 + 3) & 7) + ((s0 + 3) >> 3)) * L + 16 * (nt) + m]); \
            int p01 = pk2_fp8(v0, v1), p23 = pk2_fp8(v2, v3);                                \
            BF[d] = (p01 & 0xffff) | (p23 << 16);                                            \
        }                                                                                    \
    }
    i32x8 Bf0, Bf1;
    LDB(Bf0, 2 * w) LDB(Bf1, 2 * w + 1)

    float eTpa = __expf(T[ja * L + PAD_ID]);
    float eTpb = __expf(T[jb * L + PAD_ID]);

    // ---- fs0, exact block max -> S, q0 ----
    float fa  = emit[b * L + ja] + T[START_ID * L + ja];
    float fbv = emit[b * L + jb] + T[START_ID * L + jb];
    float mx = fmaxf(fa, fbv);
    #pragma unroll
    for (int off = 32; off; off >>= 1) mx = fmaxf(mx, __shfl_xor(mx, off, 64));
    if (lane == 0) fsx[w] = mx;
    __syncthreads();
    float S = fmaxf(fmaxf(fsx[0], fsx[1]), fmaxf(fsx[2], fsx[3]));
    float p0 = __expf(fa - S), p1 = __expf(fbv - S);
    if (g == 0)
        *(short*)&qs[0][8 * m + 2 * w] = (short)(pk2_fp8(p0, p1) & 0xffff);
    __syncthreads();

    const f32x4 z = {0.f, 0.f, 0.f, 0.f};

    // ---- phased scan: stage emit[t] rows into LDS (bf16), then VMEM-free steps ----
    int t = 1;
    while (t < len) {
        const int tbase = t;
        const int tend  = (len < tbase + PHASE_T) ? len : (tbase + PHASE_T);
        // stage rows [tbase, tend): one wave-iteration covers one row, coalesced
        {
            const int nrow = tend - tbase;
            for (int idx = tid; idx < nrow * 64; idx += 256) {
                int r = idx >> 6, c2 = (idx & 63) * 2;
                const float* ep = emit + ((size_t)(tbase + r) * BATCH + b) * L + c2;
                float e0 = ep[0], e1 = ep[1];
                unsigned int pk = (unsigned int)f2bf(e0) |
                                  ((unsigned int)f2bf(e1) << 16);
                *(unsigned int*)&elds[r * L + c2] = pk;
            }
        }
        __syncthreads();   // staging visible; also drains the staging vmcnt once/phase

        for (; t < tend; ++t) {
            const int rb = (t - 1) & 1, wb = t & 1;
            const int r = t - tbase;

            i32x4 alo = *(const i32x4*)&qs[rb][32 * g];
            i32x4 ahi = *(const i32x4*)&qs[rb][32 * g + 16];
            unsigned int hd = *(const unsigned int*)&hb[rb * 4];
            float ea = bf2f(elds[r * L + ja]);
            float eb = bf2f(elds[r * L + jb]);
            float xe0 = __expf(ea), xe1 = __expf(eb);   // under the MFMA span

            // exact uniform max of q_{t-1}: 4 hint bytes -> u8 max -> decode
            {
                const unsigned int M = 0x00FF00FFu;
                unsigned int v = umax2(hd & M, (hd >> 8) & M);
                u16x2 tv = __builtin_bit_cast(u16x2, v);
                hd = (unsigned int)(tv.x > tv.y ? tv.x : tv.y);
            }
            float msc = fp8dec(hd);
            float kk = frcp(msc);

            i32x8 A;
            A[0] = alo[0]; A[1] = alo[1]; A[2] = alo[2]; A[3] = alo[3];
            A[4] = ahi[0]; A[5] = ahi[1]; A[6] = ahi[2]; A[7] = ahi[3];

            f32x4 c0 = __builtin_amdgcn_mfma_scale_f32_16x16x128_f8f6f4(A, Bf0, z, 0, 0, 0, 127, 0, 127);
            f32x4 c1 = __builtin_amdgcn_mfma_scale_f32_16x16x128_f8f6f4(A, Bf1, z, 0, 0, 0, 127, 0, 127);

            // per-quad exact byte-max of A -> hint for next step (off critical path)
            unsigned int qm = bmax8(__builtin_bit_cast(u32x4, alo),
                                    __builtin_bit_cast(u32x4, ahi));
            if (w == 0 && m == 0) hb[wb * 4 + g] = (unsigned char)qm;

            p0 = fminf(c0[0] * kk * xe0, 400.f);   // rows replicated: c[0] valid
            p1 = fminf(c1[0] * kk * xe1, 400.f);
            if (g == 0)
                *(short*)&qs[wb][8 * m + 2 * w] = (short)(pk2_fp8(p0, p1) & 0xffff);
            S += __logf(msc);
            __syncthreads();   // lgkmcnt-only drain: no VMEM in flight here
        }
    }

    // ---- encode_b = S + log(sum_j q_j * expT[j][PAD]) (dedup over g) ----
    float ev = (g == 0) ? (p0 * eTpa + p1 * eTpb) : 0.f;
    #pragma unroll
    for (int off = 32; off; off >>= 1) ev += __shfl_xor(ev, off, 64);
    if (lane == 0) part[w] = ev;

    // ---- gold_b over all 256 threads (exact f32 emit from global) ----
    float gsum = 0.f;
    for (int tt = tid; tt < len; tt += 256) {
        int nxt = labels[b * S_LEN + tt];
        int prv = tt ? labels[b * S_LEN + tt - 1] : START_ID;
        gsum += emit[((size_t)tt * BATCH + b) * L + nxt] + T[prv * L + nxt];
        if (tt == len - 1) gsum += T[nxt * L + PAD_ID];
    }
    #pragma unroll
    for (int off = 32; off; off >>= 1) gsum += __shfl_xor(gsum, off, 64);
    if (lane == 0) part[4 + w] = gsum;
    __syncthreads();

    if (tid == 0) {
        float enc  = S + __logf((part[0] + part[1]) + (part[2] + part[3]));
        float gold = (part[4] + part[5]) + (part[6] + part[7]);
        atomicAdd(out, enc - gold);
    }
}

extern "C" void kernel_launch(void* const* d_in, const int* in_sizes, int n_in,
                              void* d_out, int out_size, void* d_ws, size_t ws_size,
                              hipStream_t stream) {
    const float* emit   = (const float*)d_in[0];
    const int*   labels = (const int*)d_in[1];
    const void*  masks  = d_in[2];
    const float* T      = (const float*)d_in[3];
    float* out = (float*)d_out;

    hipMemsetAsync(d_out, 0, sizeof(float), stream);
    k_scan<<<dim3(BATCH), dim3(256), 0, stream>>>(emit, labels, masks, T, out);
}

// Round 11
// 234.790 us; speedup vs baseline: 1.4850x; 1.2760x over previous
//
#include <hip/hip_runtime.h>
#include <hip/hip_fp8.h>

#define S_LEN 512
#define BATCH 256
#define L 128
#define PAD_ID 0
#define START_ID 1

typedef int    i32x8 __attribute__((ext_vector_type(8)));
typedef int    i32x4 __attribute__((ext_vector_type(4)));
typedef float  f32x4 __attribute__((ext_vector_type(4)));
typedef unsigned int   u32x4 __attribute__((ext_vector_type(4)));
typedef unsigned short u16x2 __attribute__((ext_vector_type(2)));

__device__ __forceinline__ unsigned int umax2(unsigned int a, unsigned int b) {
    u16x2 x = __builtin_bit_cast(u16x2, a), y = __builtin_bit_cast(u16x2, b);
#if defined(__has_builtin) && __has_builtin(__builtin_elementwise_max)
    return __builtin_bit_cast(unsigned int, __builtin_elementwise_max(x, y));  // v_pk_max_u16
#else
    u16x2 r; r.x = x.x > y.x ? x.x : y.x; r.y = x.y > y.y ? x.y : y.y;
    return __builtin_bit_cast(unsigned int, r);
#endif
}
__device__ __forceinline__ float frcp(float x) {
#if defined(__has_builtin) && __has_builtin(__builtin_amdgcn_rcpf)
    return __builtin_amdgcn_rcpf(x);
#else
    return 1.0f / x;
#endif
}
__device__ __forceinline__ unsigned short f2bf(float f) {   // RNE f32->bf16
    unsigned int u = __builtin_bit_cast(unsigned int, f);
    return (unsigned short)((u + 0x7fffu + ((u >> 16) & 1u)) >> 16);
}
__device__ __forceinline__ float bf2f(unsigned short b) {
    return __builtin_bit_cast(float, (unsigned int)b << 16);
}
// NaN-killing sanitizer: fmaxf(NaN, lo) = lo on AMD (IEEE maxNum) -> result always
// in [lo, hi], never NaN/Inf. Applied at EVERY step boundary before fp8 store.
__device__ __forceinline__ float sane(float x, float lo, float hi) {
    return fminf(fmaxf(x, lo), hi);
}
__device__ __forceinline__ int pk2_fp8(float a, float b) {
#if defined(__has_builtin) && __has_builtin(__builtin_amdgcn_cvt_pk_fp8_f32)
    return __builtin_amdgcn_cvt_pk_fp8_f32(a, b, 0, false);
#else
    __hip_fp8_e4m3 A(a), B(b);
    return (int)A.__x | ((int)B.__x << 8);
#endif
}
// exact max byte (u8) over 8 dwords of positive-e4m3 bytes, via even/odd u16 lanes
__device__ __forceinline__ unsigned int bmax8(u32x4 a, u32x4 b) {
    const unsigned int M = 0x00FF00FFu;
    unsigned int l0 = umax2(a.x & M, a.y & M), l1 = umax2(a.z & M, a.w & M);
    unsigned int l2 = umax2(b.x & M, b.y & M), l3 = umax2(b.z & M, b.w & M);
    unsigned int h0 = umax2((a.x >> 8) & M, (a.y >> 8) & M);
    unsigned int h1 = umax2((a.z >> 8) & M, (a.w >> 8) & M);
    unsigned int h2 = umax2((b.x >> 8) & M, (b.y >> 8) & M);
    unsigned int h3 = umax2((b.z >> 8) & M, (b.w >> 8) & M);
    unsigned int v = umax2(umax2(umax2(l0, l1), umax2(l2, l3)),
                           umax2(umax2(h0, h1), umax2(h2, h3)));
    u16x2 t = __builtin_bit_cast(u16x2, v);
    return (unsigned int)(t.x > t.y ? t.x : t.y);
}
__device__ __forceinline__ float fp8dec(unsigned int bb) {   // e4m3 byte -> float
    bb &= 0x7Fu;                                  // defensive: never decode NaN slot
    int e = (int)(bb >> 3), mt = (int)(bb & 7u);
    float v = e ? __builtin_ldexpf((float)(8 + mt), e - 10)
                : __builtin_ldexpf((float)mt, -9);
    return sane(v, 1e-9f, 448.f);
}

// MEET-IN-THE-MIDDLE CRF scan (r11 = r10 + full LDS-state init + structural NaN-kill).
// encode_b = log(q0^T (prod_t E diag(x_t)) w); forward chain (waves 0-3) meets backward
// chain u_t = x_t o (E u_{t+1}) (waves 4-7) at kf = n/2; join v = (E^T q_kf) . u_{kf+1}.
// Serial steps 511 -> ~256. Per-chain step = r9's validated structure (fp8 state,
// 2x mfma_scale_16x16x128/wave, exact u8-hint max, 1 barrier/step). All emit rows
// staged once in LDS as bf16 (128 KB) -> VMEM-free hot loop.
__global__ __launch_bounds__(512, 1) void k_scan(
        const float* __restrict__ emit, const int* __restrict__ labels,
        const void* __restrict__ masks, const float* __restrict__ T,
        float* __restrict__ out) {
    const int b = blockIdx.x;
    const int tid = threadIdx.x;
    const int w = tid >> 6;                  // wave 0..7
    const int dir = w >> 2;                  // 0 = forward, 1 = backward
    const int wl = w & 3;                    // wave-in-group
    const int lane = tid & 63;
    const int g = lane >> 4, m = lane & 15;  // quad (k-chunk), col
    const int ja = 32 * wl + m, jb = ja + 16;

    __shared__ unsigned short elds[512][L];              // emit rows 1..n, bf16 (128KB)
    __shared__ __align__(16) unsigned char qs[2][2][L];  // [dir][buf][slot]
    __shared__ __align__(16) unsigned char hb[2][2][4];  // [dir][buf][quad] hint bytes
    __shared__ float part[12];                           // [0..3] ev, [4..11] gold
    __shared__ float fsx[8];
    __shared__ float Ssh[2];
    __shared__ int   ib[8];

    // ---- FULL init of all cross-wave LDS state (r11: no unwritten-buffer reads) ----
    {
        const unsigned int* mw0 = (const unsigned int*)masks;
        int pred = 0;
        #pragma unroll
        for (int k = 0; k < 4; ++k) {
            unsigned int w0 = mw0[tid + 512 * k];
            pred |= (w0 > 1u && w0 != 0x3f800000u);
        }
        unsigned long long bal = __ballot(pred);
        if (lane == 0) ib[w] = (bal != 0ull) ? 1 : 0;
        if (tid < 16)  ((unsigned char*)hb)[tid] = 0x38;     // fp8(1.0)
        if (tid < 512) ((unsigned char*)qs)[tid] = 0x38;     // all 4 q/u buffers = 1.0
        if (tid < 12)  part[tid] = 0.f;
        if (tid < 8)   fsx[tid] = 0.f;
        if (tid < 2)   Ssh[tid] = 0.f;
    }
    __syncthreads();
    const bool isbyte = (ib[0] | ib[1] | ib[2] | ib[3] | ib[4] | ib[5] | ib[6] | ib[7]) != 0;

    // ---- len of row b (prefix-ones mask; per-wave redundant, uniform) ----
    int len;
    {
        int cnt = 0;
        if (isbyte) {
            const unsigned int* mw = (const unsigned int*)masks + b * (S_LEN / 4);
            #pragma unroll
            for (int k = 0; k < 2; ++k) {
                unsigned int w0 = mw[lane + 64 * k];
                cnt += ((w0 & 0xffu) != 0) + ((w0 & 0xff00u) != 0) +
                       ((w0 & 0xff0000u) != 0) + ((w0 & 0xff000000u) != 0);
            }
        } else {
            const unsigned int* mw = (const unsigned int*)masks + b * S_LEN;
            #pragma unroll
            for (int k = 0; k < 8; ++k) cnt += (mw[lane + 64 * k] != 0u);
        }
        #pragma unroll
        for (int off = 32; off; off >>= 1) cnt += __shfl_xor(cnt, off, 64);
        len = cnt;
    }
    const int n  = len - 1;          // number of transition matrices
    const int kf = n / 2;            // forward steps
    const int nB = n - kf - 1;       // backward steps

    // ---- B-frags: byte slot s = 32g+4d+y, j(s) = 16*(s&7)+(s>>3).
    //      forward (E^T matvec): B[s][col] = expT[j(s)][col]
    //      backward (E matvec):  B[s][col] = expT[col][j(s)] ----
#define LDBX(BF, nt, TR)                                                                     \
    {                                                                                        \
        _Pragma("unroll")                                                                    \
        for (int d = 0; d < 8; ++d) {                                                        \
            int s0 = 32 * g + 4 * d;                                                         \
            float v0, v1, v2, v3;                                                            \
            if (TR) {                                                                        \
                v0 = __expf(T[(16 * (nt) + m) * L + (16 * ((s0 + 0) & 7) + ((s0 + 0) >> 3))]); \
                v1 = __expf(T[(16 * (nt) + m) * L + (16 * ((s0 + 1) & 7) + ((s0 + 1) >> 3))]); \
                v2 = __expf(T[(16 * (nt) + m) * L + (16 * ((s0 + 2) & 7) + ((s0 + 2) >> 3))]); \
                v3 = __expf(T[(16 * (nt) + m) * L + (16 * ((s0 + 3) & 7) + ((s0 + 3) >> 3))]); \
            } else {                                                                         \
                v0 = __expf(T[(16 * ((s0 + 0) & 7) + ((s0 + 0) >> 3)) * L + 16 * (nt) + m]);   \
                v1 = __expf(T[(16 * ((s0 + 1) & 7) + ((s0 + 1) >> 3)) * L + 16 * (nt) + m]);   \
                v2 = __expf(T[(16 * ((s0 + 2) & 7) + ((s0 + 2) >> 3)) * L + 16 * (nt) + m]);   \
                v3 = __expf(T[(16 * ((s0 + 3) & 7) + ((s0 + 3) >> 3)) * L + 16 * (nt) + m]);   \
            }                                                                                \
            int p01 = pk2_fp8(v0, v1), p23 = pk2_fp8(v2, v3);                                \
            BF[d] = (p01 & 0xffff) | (p23 << 16);                                            \
        }                                                                                    \
    }
    i32x8 Bq0, Bq1;
    if (dir == 0) { LDBX(Bq0, 2 * wl, 0) LDBX(Bq1, 2 * wl + 1, 0) }
    else          { LDBX(Bq0, 2 * wl, 1) LDBX(Bq1, 2 * wl + 1, 1) }

    const float eTpa = T[ja * L + PAD_ID];
    const float eTpb = T[jb * L + PAD_ID];

    // ---- stage ALL emit rows 1..n into LDS as bf16 (coalesced float2->b32) ----
    for (int idx = tid; idx < n * 64; idx += 512) {
        int r = 1 + (idx >> 6), c2 = (idx & 63) * 2;
        const float* ep = emit + ((size_t)r * BATCH + b) * L + c2;
        float e0 = ep[0], e1 = ep[1];
        *(unsigned int*)&elds[r][c2] =
            (unsigned int)f2bf(e0) | ((unsigned int)f2bf(e1) << 16);
    }
    __syncthreads();

    // ---- inits: forward q0 (exact emit row 0); backward u_n = x_n o w (exact row n) ----
    float fa = 0.f, fbv = 0.f;
    if (dir == 0) {
        fa  = emit[b * L + ja] + T[START_ID * L + ja];
        fbv = emit[b * L + jb] + T[START_ID * L + jb];
    } else if (n >= 1) {
        fa  = emit[((size_t)n * BATCH + b) * L + ja] + eTpa;
        fbv = emit[((size_t)n * BATCH + b) * L + jb] + eTpb;
    }
    {
        float mx = fmaxf(fa, fbv);
        #pragma unroll
        for (int off = 32; off; off >>= 1) mx = fmaxf(mx, __shfl_xor(mx, off, 64));
        if (lane == 0) fsx[w] = mx;
    }
    __syncthreads();
    float S = 0.f, p0 = 0.f, p1 = 0.f;
    if (dir == 0 || n >= 1) {
        S = dir ? fmaxf(fmaxf(fsx[4], fsx[5]), fmaxf(fsx[6], fsx[7]))
                : fmaxf(fmaxf(fsx[0], fsx[1]), fmaxf(fsx[2], fsx[3]));
        p0 = sane(__expf(fa - S), 1e-9f, 400.f);
        p1 = sane(__expf(fbv - S), 1e-9f, 400.f);
        if (g == 0)
            *(short*)&qs[dir][0][8 * m + 2 * wl] = (short)(pk2_fp8(p0, p1) & 0xffff);
    }
    __syncthreads();

    // ---- hot loop: kf iterations; both chains advance per barrier ----
    const f32x4 z = {0.f, 0.f, 0.f, 0.f};
    for (int i = 0; i < kf; ++i) {
        bool act = dir ? (i < nB) : true;
        if (act) {
            const int rb = i & 1, wb2 = (i + 1) & 1;
            const int row = dir ? (n - 1 - i) : (i + 1);

            i32x4 alo = *(const i32x4*)&qs[dir][rb][32 * g];
            i32x4 ahi = *(const i32x4*)&qs[dir][rb][32 * g + 16];
            unsigned int hd = *(const unsigned int*)&hb[dir][rb][0];
            float ea = bf2f(elds[row][ja]);
            float eb = bf2f(elds[row][jb]);
            float xe0 = __expf(ea), xe1 = __expf(eb);

            {   // uniform max of the 4 hint bytes (exact max of 128 state bytes, lag-1)
                const unsigned int M = 0x00FF00FFu;
                unsigned int v = umax2(hd & M, (hd >> 8) & M);
                u16x2 tv = __builtin_bit_cast(u16x2, v);
                hd = (unsigned int)(tv.x > tv.y ? tv.x : tv.y);
            }
            float msc = fp8dec(hd);
            float kk = frcp(msc);

            i32x8 A;
            A[0] = alo[0]; A[1] = alo[1]; A[2] = alo[2]; A[3] = alo[3];
            A[4] = ahi[0]; A[5] = ahi[1]; A[6] = ahi[2]; A[7] = ahi[3];

            f32x4 c0 = __builtin_amdgcn_mfma_scale_f32_16x16x128_f8f6f4(A, Bq0, z, 0, 0, 0, 127, 0, 127);
            f32x4 c1 = __builtin_amdgcn_mfma_scale_f32_16x16x128_f8f6f4(A, Bq1, z, 0, 0, 0, 127, 0, 127);

            unsigned int qm = bmax8(__builtin_bit_cast(u32x4, alo),
                                    __builtin_bit_cast(u32x4, ahi));
            if (wl == 0 && m == 0) hb[dir][wb2][g] = (unsigned char)(qm & 0x7Fu);

            p0 = sane(c0[0] * kk * xe0, 1e-9f, 400.f);   // rows replicated: c[0] valid
            p1 = sane(c1[0] * kk * xe1, 1e-9f, 400.f);
            if (g == 0)
                *(short*)&qs[dir][wb2][8 * m + 2 * wl] = (short)(pk2_fp8(p0, p1) & 0xffff);
            S += __logf(msc);
        }
        __syncthreads();
    }

    // ---- join: v = (E^T q_kf) . u_{kf+1} ----
    float ev = 0.f;
    if (n >= 1) {
        if (dir == 0) {
            const int rb = kf & 1, bufB = nB & 1;
            i32x4 alo = *(const i32x4*)&qs[0][rb][32 * g];
            i32x4 ahi = *(const i32x4*)&qs[0][rb][32 * g + 16];
            i32x8 A;
            A[0] = alo[0]; A[1] = alo[1]; A[2] = alo[2]; A[3] = alo[3];
            A[4] = ahi[0]; A[5] = ahi[1]; A[6] = ahi[2]; A[7] = ahi[3];
            f32x4 c0 = __builtin_amdgcn_mfma_scale_f32_16x16x128_f8f6f4(A, Bq0, z, 0, 0, 0, 127, 0, 127);
            f32x4 c1 = __builtin_amdgcn_mfma_scale_f32_16x16x128_f8f6f4(A, Bq1, z, 0, 0, 0, 127, 0, 127);
            if (g == 0) {
                float ua = fp8dec(qs[1][bufB][8 * m + 2 * wl]);
                float ub = fp8dec(qs[1][bufB][8 * m + 2 * wl + 1]);
                ev = sane(c0[0], 0.f, 3e7f) * ua + sane(c1[0], 0.f, 3e7f) * ub;
            }
        }
    } else {
        if (dir == 0 && g == 0) ev = p0 * __expf(eTpa) + p1 * __expf(eTpb);
    }
    #pragma unroll
    for (int off = 32; off; off >>= 1) ev += __shfl_xor(ev, off, 64);
    if (dir == 0 && lane == 0) part[wl] = ev;
    if (tid == 0) Ssh[0] = S;
    if (w == 4 && lane == 0 && n >= 1) Ssh[1] = S;

    // ---- gold_b over all 512 threads (exact f32 emit) ----
    float gsum = 0.f;
    for (int tt = tid; tt < len; tt += 512) {
        int nxt = labels[b * S_LEN + tt];
        int prv = tt ? labels[b * S_LEN + tt - 1] : START_ID;
        gsum += emit[((size_t)tt * BATCH + b) * L + nxt] + T[prv * L + nxt];
        if (tt == len - 1) gsum += T[nxt * L + PAD_ID];
    }
    #pragma unroll
    for (int off = 32; off; off >>= 1) gsum += __shfl_xor(gsum, off, 64);
    if (lane == 0) part[4 + w] = gsum;
    __syncthreads();

    if (tid == 0) {
        float evs = fmaxf((part[0] + part[1]) + (part[2] + part[3]), 1e-35f);
        float enc  = Ssh[0] + Ssh[1] + __logf(evs);
        float gold = ((part[4] + part[5]) + (part[6] + part[7])) +
                     ((part[8] + part[9]) + (part[10] + part[11]));
        float contrib = sane(enc - gold, -1e30f, 1e30f);   // guaranteed finite
        atomicAdd(out, contrib);
    }
}

extern "C" void kernel_launch(void* const* d_in, const int* in_sizes, int n_in,
                              void* d_out, int out_size, void* d_ws, size_t ws_size,
                              hipStream_t stream) {
    const float* emit   = (const float*)d_in[0];
    const int*   labels = (const int*)d_in[1];
    const void*  masks  = d_in[2];
    const float* T      = (const float*)d_in[3];
    float* out = (float*)d_out;

    hipMemsetAsync(d_out, 0, sizeof(float), stream);
    k_scan<<<dim3(BATCH), dim3(512), 0, stream>>>(emit, labels, masks, T, out);
}

// Round 12
// 227.858 us; speedup vs baseline: 1.5302x; 1.0304x over previous
//
#include <hip/hip_runtime.h>
#include <hip/hip_fp8.h>

#define S_LEN 512
#define BATCH 256
#define L 128
#define PAD_ID 0
#define START_ID 1

typedef int    i32x8 __attribute__((ext_vector_type(8)));
typedef int    i32x4 __attribute__((ext_vector_type(4)));
typedef float  f32x4 __attribute__((ext_vector_type(4)));
typedef unsigned int   u32x4 __attribute__((ext_vector_type(4)));
typedef unsigned short u16x2 __attribute__((ext_vector_type(2)));

__device__ __forceinline__ unsigned int umax2(unsigned int a, unsigned int b) {
    u16x2 x = __builtin_bit_cast(u16x2, a), y = __builtin_bit_cast(u16x2, b);
#if defined(__has_builtin) && __has_builtin(__builtin_elementwise_max)
    return __builtin_bit_cast(unsigned int, __builtin_elementwise_max(x, y));  // v_pk_max_u16
#else
    u16x2 r; r.x = x.x > y.x ? x.x : y.x; r.y = x.y > y.y ? x.y : y.y;
    return __builtin_bit_cast(unsigned int, r);
#endif
}
__device__ __forceinline__ float frcp(float x) {
#if defined(__has_builtin) && __has_builtin(__builtin_amdgcn_rcpf)
    return __builtin_amdgcn_rcpf(x);
#else
    return 1.0f / x;
#endif
}
__device__ __forceinline__ unsigned short f2bf(float f) {   // RNE f32->bf16
    unsigned int u = __builtin_bit_cast(unsigned int, f);
    return (unsigned short)((u + 0x7fffu + ((u >> 16) & 1u)) >> 16);
}
__device__ __forceinline__ float bf2f(unsigned short b) {
    return __builtin_bit_cast(float, (unsigned int)b << 16);
}
// NaN-killing sanitizer (fmaxf(NaN,lo)=lo on AMD): result always in [lo,hi], never NaN.
__device__ __forceinline__ float sane(float x, float lo, float hi) {
    return fminf(fmaxf(x, lo), hi);
}
__device__ __forceinline__ int pk2_fp8(float a, float b) {
#if defined(__has_builtin) && __has_builtin(__builtin_amdgcn_cvt_pk_fp8_f32)
    return __builtin_amdgcn_cvt_pk_fp8_f32(a, b, 0, false);
#else
    __hip_fp8_e4m3 A(a), B(b);
    return (int)A.__x | ((int)B.__x << 8);
#endif
}
// exact max byte (u8) over 8 dwords of positive-e4m3 bytes, via even/odd u16 lanes
__device__ __forceinline__ unsigned int bmax8(u32x4 a, u32x4 b) {
    const unsigned int M = 0x00FF00FFu;
    unsigned int l0 = umax2(a.x & M, a.y & M), l1 = umax2(a.z & M, a.w & M);
    unsigned int l2 = umax2(b.x & M, b.y & M), l3 = umax2(b.z & M, b.w & M);
    unsigned int h0 = umax2((a.x >> 8) & M, (a.y >> 8) & M);
    unsigned int h1 = umax2((a.z >> 8) & M, (a.w >> 8) & M);
    unsigned int h2 = umax2((b.x >> 8) & M, (b.y >> 8) & M);
    unsigned int h3 = umax2((b.z >> 8) & M, (b.w >> 8) & M);
    unsigned int v = umax2(umax2(umax2(l0, l1), umax2(l2, l3)),
                           umax2(umax2(h0, h1), umax2(h2, h3)));
    u16x2 t = __builtin_bit_cast(u16x2, v);
    return (unsigned int)(t.x > t.y ? t.x : t.y);
}
__device__ __forceinline__ float fp8dec(unsigned int bb) {   // e4m3 byte -> float
    bb &= 0x7Fu;
    int e = (int)(bb >> 3), mt = (int)(bb & 7u);
    float v = e ? __builtin_ldexpf((float)(8 + mt), e - 10)
                : __builtin_ldexpf((float)mt, -9);
    return sane(v, 1e-9f, 448.f);
}

// ws layout: qf[256][128] fp8 | qb[256][128] fp8 | Sf[256] f32 | Sb[256] f32 | nArr[256] i32
#define WS_QF 0
#define WS_QB 32768
#define WS_SF 65536
#define WS_SB 66560
#define WS_N  67584

// r12: forward and backward chains in SEPARATE 4-wave blocks (512 blocks, one launch).
// Each block = r9's validated step (fp8 state, 2x mfma_scale_16x16x128/wave, exact
// u8-hint max, one 4-wave barrier/step), its half of the emit rows in LDS (<=255 rows
// bf16 = 65.3KB -> 2 blocks/CU, all 512 co-resident). r11 lesson: one 8-wave barrier
// costs ~+40%/step vs 4-wave; the two chains never needed to sync until the join.
// Seam q_kf / u_{kf+1} + scale S go to d_ws; k_join does the exact-f32 join.
__global__ __launch_bounds__(256, 1) void k_scan2(
        const float* __restrict__ emit, const int* __restrict__ labels,
        const void* __restrict__ masks, const float* __restrict__ T,
        unsigned char* __restrict__ ws, float* __restrict__ out) {
    const int b   = blockIdx.x & (BATCH - 1);
    const int dir = blockIdx.x >> 8;         // 0 = forward, 1 = backward
    const int tid = threadIdx.x;
    const int w = tid >> 6;                  // wave 0..3
    const int lane = tid & 63;
    const int g = lane >> 4, m = lane & 15;  // quad (k-chunk), col
    const int ja = 32 * w + m, jb = ja + 16; // this wave's two output labels

    __shared__ unsigned short elds[255][L];              // emit rows (this dir's half)
    __shared__ __align__(16) unsigned char qs[2][L];     // state, double-buffered
    __shared__ __align__(8)  unsigned char hb[2][4];     // hint bytes [buf][quad]
    __shared__ float part[4];
    __shared__ float fsx[4];
    __shared__ int   ib[4];

    // ---- init block-shared state + mask encoding self-detect (first 8KB) ----
    {
        const unsigned int* mw0 = (const unsigned int*)masks;
        int pred = 0;
        #pragma unroll
        for (int k = 0; k < 8; ++k) {
            unsigned int w0 = mw0[tid + 256 * k];
            pred |= (w0 > 1u && w0 != 0x3f800000u);
        }
        unsigned long long bal = __ballot(pred);
        if (lane == 0) ib[w] = (bal != 0ull) ? 1 : 0;
        if (tid < 8)   ((unsigned char*)hb)[tid] = 0x38;   // fp8(1.0)
        if (tid < 256) ((unsigned char*)qs)[tid] = 0x38;   // both buffers = 1.0
        if (tid < 4)   { part[tid] = 0.f; fsx[tid] = 0.f; }
    }
    __syncthreads();
    const bool isbyte = (ib[0] | ib[1] | ib[2] | ib[3]) != 0;

    // ---- len of row b (prefix-ones mask; per-wave redundant, uniform) ----
    int len;
    {
        int cnt = 0;
        if (isbyte) {
            const unsigned int* mw = (const unsigned int*)masks + b * (S_LEN / 4);
            #pragma unroll
            for (int k = 0; k < 2; ++k) {
                unsigned int w0 = mw[lane + 64 * k];
                cnt += ((w0 & 0xffu) != 0) + ((w0 & 0xff00u) != 0) +
                       ((w0 & 0xff0000u) != 0) + ((w0 & 0xff000000u) != 0);
            }
        } else {
            const unsigned int* mw = (const unsigned int*)masks + b * S_LEN;
            #pragma unroll
            for (int k = 0; k < 8; ++k) cnt += (mw[lane + 64 * k] != 0u);
        }
        #pragma unroll
        for (int off = 32; off; off >>= 1) cnt += __shfl_xor(cnt, off, 64);
        len = cnt;
    }
    const int n  = len - 1;
    const int kf = n / 2;                    // forward steps
    const int nB = n - kf - 1;               // backward steps (may be <0 for n=0)
    const int steps = dir ? (nB > 0 ? nB : 0) : kf;

    // ---- B-frags: byte slot s = 32g+4d+y, j(s) = 16*(s&7)+(s>>3).
    //      forward (E^T matvec): B[s][col] = expT[j(s)][col]
    //      backward (E matvec):  B[s][col] = expT[col][j(s)] ----
#define LDBX(BF, nt, TR)                                                                     \
    {                                                                                        \
        _Pragma("unroll")                                                                    \
        for (int d = 0; d < 8; ++d) {                                                        \
            int s0 = 32 * g + 4 * d;                                                         \
            float v0, v1, v2, v3;                                                            \
            if (TR) {                                                                        \
                v0 = __expf(T[(16 * (nt) + m) * L + (16 * ((s0 + 0) & 7) + ((s0 + 0) >> 3))]); \
                v1 = __expf(T[(16 * (nt) + m) * L + (16 * ((s0 + 1) & 7) + ((s0 + 1) >> 3))]); \
                v2 = __expf(T[(16 * (nt) + m) * L + (16 * ((s0 + 2) & 7) + ((s0 + 2) >> 3))]); \
                v3 = __expf(T[(16 * (nt) + m) * L + (16 * ((s0 + 3) & 7) + ((s0 + 3) >> 3))]); \
            } else {                                                                         \
                v0 = __expf(T[(16 * ((s0 + 0) & 7) + ((s0 + 0) >> 3)) * L + 16 * (nt) + m]);   \
                v1 = __expf(T[(16 * ((s0 + 1) & 7) + ((s0 + 1) >> 3)) * L + 16 * (nt) + m]);   \
                v2 = __expf(T[(16 * ((s0 + 2) & 7) + ((s0 + 2) >> 3)) * L + 16 * (nt) + m]);   \
                v3 = __expf(T[(16 * ((s0 + 3) & 7) + ((s0 + 3) >> 3)) * L + 16 * (nt) + m]);   \
            }                                                                                \
            int p01 = pk2_fp8(v0, v1), p23 = pk2_fp8(v2, v3);                                \
            BF[d] = (p01 & 0xffff) | (p23 << 16);                                            \
        }                                                                                    \
    }
    i32x8 Bq0, Bq1;
    if (dir == 0) { LDBX(Bq0, 2 * w, 0) LDBX(Bq1, 2 * w + 1, 0) }
    else          { LDBX(Bq0, 2 * w, 1) LDBX(Bq1, 2 * w + 1, 1) }

    // ---- stage this dir's emit rows into LDS as bf16 (coalesced float2->b32):
    //      forward: rows 1..kf -> slot r-1; backward: rows kf+1..n-1 -> slot r-(kf+1) ----
    for (int idx = tid; idx < steps * 64; idx += 256) {
        int rl = idx >> 6, c2 = (idx & 63) * 2;
        int row = dir ? (kf + 1 + rl) : (1 + rl);
        const float* ep = emit + ((size_t)row * BATCH + b) * L + c2;
        float e0 = ep[0], e1 = ep[1];
        *(unsigned int*)&elds[rl][c2] =
            (unsigned int)f2bf(e0) | ((unsigned int)f2bf(e1) << 16);
    }

    // ---- init state: fwd q0 (emit row 0); bwd u_n = x_n o w (emit row n, exact) ----
    float fa = 0.f, fbv = 0.f;
    const bool active = (dir == 0) || (n >= 1);
    if (dir == 0) {
        fa  = emit[b * L + ja] + T[START_ID * L + ja];
        fbv = emit[b * L + jb] + T[START_ID * L + jb];
    } else if (n >= 1) {
        fa  = emit[((size_t)n * BATCH + b) * L + ja] + T[ja * L + PAD_ID];
        fbv = emit[((size_t)n * BATCH + b) * L + jb] + T[jb * L + PAD_ID];
    }
    {
        float mx = fmaxf(fa, fbv);
        #pragma unroll
        for (int off = 32; off; off >>= 1) mx = fmaxf(mx, __shfl_xor(mx, off, 64));
        if (lane == 0) fsx[w] = mx;
    }
    __syncthreads();   // also makes staged emit visible
    float S = 0.f, p0 = 0.f, p1 = 0.f;
    if (active) {
        S = fmaxf(fmaxf(fsx[0], fsx[1]), fmaxf(fsx[2], fsx[3]));
        p0 = sane(__expf(fa - S), 1e-9f, 400.f);
        p1 = sane(__expf(fbv - S), 1e-9f, 400.f);
        if (g == 0)
            *(short*)&qs[0][8 * m + 2 * w] = (short)(pk2_fp8(p0, p1) & 0xffff);
    }
    __syncthreads();

    // ---- hot loop (r9 step, 4-wave barrier) ----
    const f32x4 z = {0.f, 0.f, 0.f, 0.f};
    for (int i = 0; i < steps; ++i) {
        const int rb = i & 1, wb2 = (i + 1) & 1;
        const int slot = dir ? (nB - 1 - i) : i;

        i32x4 alo = *(const i32x4*)&qs[rb][32 * g];
        i32x4 ahi = *(const i32x4*)&qs[rb][32 * g + 16];
        unsigned int hd = *(const unsigned int*)&hb[rb][0];
        float ea = bf2f(elds[slot][ja]);
        float eb = bf2f(elds[slot][jb]);
        float xe0 = __expf(ea), xe1 = __expf(eb);

        {   // uniform max of the 4 hint bytes (exact max of all 128 state bytes)
            const unsigned int M = 0x00FF00FFu;
            unsigned int v = umax2(hd & M, (hd >> 8) & M);
            u16x2 tv = __builtin_bit_cast(u16x2, v);
            hd = (unsigned int)(tv.x > tv.y ? tv.x : tv.y);
        }
        float msc = fp8dec(hd);
        float kk = frcp(msc);

        i32x8 A;
        A[0] = alo[0]; A[1] = alo[1]; A[2] = alo[2]; A[3] = alo[3];
        A[4] = ahi[0]; A[5] = ahi[1]; A[6] = ahi[2]; A[7] = ahi[3];

        f32x4 c0 = __builtin_amdgcn_mfma_scale_f32_16x16x128_f8f6f4(A, Bq0, z, 0, 0, 0, 127, 0, 127);
        f32x4 c1 = __builtin_amdgcn_mfma_scale_f32_16x16x128_f8f6f4(A, Bq1, z, 0, 0, 0, 127, 0, 127);

        unsigned int qm = bmax8(__builtin_bit_cast(u32x4, alo),
                                __builtin_bit_cast(u32x4, ahi));
        if (w == 0 && m == 0) hb[wb2][g] = (unsigned char)(qm & 0x7Fu);

        p0 = sane(c0[0] * kk * xe0, 1e-9f, 400.f);   // rows replicated: c[0] valid
        p1 = sane(c1[0] * kk * xe1, 1e-9f, 400.f);
        if (g == 0)
            *(short*)&qs[wb2][8 * m + 2 * w] = (short)(pk2_fp8(p0, p1) & 0xffff);
        S += __logf(msc);
        __syncthreads();
    }

    // ---- seam + scale to ws ----
    unsigned char* seam = ws + (dir ? WS_QB : WS_QF) + b * L;
    if (tid < 32) ((int*)seam)[tid] = ((const int*)qs[steps & 1])[tid];
    if (tid == 0) {
        ((float*)(ws + (dir ? WS_SB : WS_SF)))[b] = S;
        if (dir == 0) ((int*)(ws + WS_N))[b] = n;
    }

    // ---- gold (forward block only; exact f32) -> out ----
    if (dir == 0) {
        float gsum = 0.f;
        for (int tt = tid; tt < len; tt += 256) {
            int nxt = labels[b * S_LEN + tt];
            int prv = tt ? labels[b * S_LEN + tt - 1] : START_ID;
            gsum += emit[((size_t)tt * BATCH + b) * L + nxt] + T[prv * L + nxt];
            if (tt == len - 1) gsum += T[nxt * L + PAD_ID];
        }
        #pragma unroll
        for (int off = 32; off; off >>= 1) gsum += __shfl_xor(gsum, off, 64);
        if (lane == 0) part[w] = gsum;
        __syncthreads();
        if (tid == 0)
            atomicAdd(out, -((part[0] + part[1]) + (part[2] + part[3])));
    }
}

// Exact-f32 join: enc_b = Sf + Sb + log(q_kf^T E u_{kf+1})  (n=0: Sf + log(q0.expTpad))
__global__ __launch_bounds__(64, 1) void k_join(
        const float* __restrict__ T, const unsigned char* __restrict__ ws,
        float* __restrict__ out) {
    const int b = blockIdx.x;
    const int lane = threadIdx.x;
    __shared__ float qsh[L], ush[L];

    const int n = ((const int*)(ws + WS_N))[b];
    // decode seam bytes (store-order slot s -> label 16*(s&7)+(s>>3))
    #pragma unroll
    for (int k = 0; k < 2; ++k) {
        int s = lane + 64 * k;
        int j = 16 * (s & 7) + (s >> 3);
        qsh[j] = fp8dec(ws[WS_QF + b * L + s]);
        ush[j] = fp8dec(ws[WS_QB + b * L + s]);
    }
    __syncthreads();

    float ev = 0.f;
    if (n >= 1) {
        #pragma unroll
        for (int k = 0; k < 2; ++k) {
            int j = lane + 64 * k;
            float v = 0.f;
            for (int i = 0; i < L; ++i)
                v = fmaf(qsh[i], __expf(T[i * L + j]), v);
            ev += v * ush[j];
        }
    } else {
        #pragma unroll
        for (int k = 0; k < 2; ++k) {
            int j = lane + 64 * k;
            ev += qsh[j] * __expf(T[j * L + PAD_ID]);
        }
    }
    #pragma unroll
    for (int off = 32; off; off >>= 1) ev += __shfl_xor(ev, off, 64);

    if (lane == 0) {
        float Sf = ((const float*)(ws + WS_SF))[b];
        float Sb = (n >= 1) ? ((const float*)(ws + WS_SB))[b] : 0.f;
        float enc = Sf + Sb + __logf(fmaxf(ev, 1e-35f));
        atomicAdd(out, sane(enc, -1e30f, 1e30f));
    }
}

extern "C" void kernel_launch(void* const* d_in, const int* in_sizes, int n_in,
                              void* d_out, int out_size, void* d_ws, size_t ws_size,
                              hipStream_t stream) {
    const float* emit   = (const float*)d_in[0];
    const int*   labels = (const int*)d_in[1];
    const void*  masks  = d_in[2];
    const float* T      = (const float*)d_in[3];
    float* out = (float*)d_out;
    unsigned char* ws = (unsigned char*)d_ws;

    hipMemsetAsync(d_out, 0, sizeof(float), stream);
    k_scan2<<<dim3(2 * BATCH), dim3(256), 0, stream>>>(emit, labels, masks, T, ws, out);
    k_join <<<dim3(BATCH),     dim3(64),  0, stream>>>(T, ws, out);
}